// Round 4
// baseline (194.575 us; speedup 1.0000x reference)
//
#include <hip/hip_runtime.h>
#include <hip/hip_bf16.h>

typedef __attribute__((ext_vector_type(8))) short short8;
typedef __attribute__((ext_vector_type(4))) short s16x4;
typedef __attribute__((ext_vector_type(4))) float f32x4;

#define BN 4
#define PN 1024
#define NN 16
#define C1N 64
#define C2N 64
#define KN 13
#define AN 12
#define KDIM 9984   // C1N*KN*AN, kk = k*768 + c*12 + a
#define NDIM 768    // C2N*AN
#define MDIM 4096   // BN*PN
#define BK 64

__device__ inline unsigned short f2bf(float x){
    unsigned int u = __float_as_uint(x);
    unsigned int r = (u + 0x7fffu + ((u >> 16) & 1u)) >> 16;
    return (unsigned short)r;
}

// async global->LDS, 16B per lane. LDS dest = wave-uniform base + lane*16.
__device__ __forceinline__ void gload16(const unsigned short* g, unsigned short* l){
    __builtin_amdgcn_global_load_lds(
        (const __attribute__((address_space(1))) unsigned int*)(unsigned long long)(uintptr_t)g,
        (__attribute__((address_space(3))) unsigned int*)(unsigned int)(uintptr_t)l,
        16, 0, 0);
}

// ---------------- Kernel 1: inter_w softmax weights ----------------
__global__ __launch_bounds__(256) void k_interw(const int* __restrict__ nbr,
                                                const float* __restrict__ vert,
                                                const float* __restrict__ vs,
                                                float* __restrict__ iw)
{
    int t = blockIdx.x * 256 + threadIdx.x;      // < 49152
    if (t >= MDIM * AN) return;
    int pt = t / AN, a = t - pt * AN;
    int b = pt >> 10;
    float sx = vs[a*3+0], sy = vs[a*3+1], sz = vs[a*3+2];
    float sn = sqrtf(sx*sx + sy*sy + sz*sz);
    float si = 1.0f / fmaxf(sn, 1e-12f);
    sx *= si; sy *= si; sz *= si;
    float vx = vert[pt*3+0], vy = vert[pt*3+1], vz = vert[pt*3+2];
    float tt[NN];
    float mx = -1e30f;
    #pragma unroll
    for (int n = 0; n < NN; n++){
        int g = (b << 10) + nbr[pt*NN + n];
        float dx = vert[g*3+0] - vx;
        float dy = vert[g*3+1] - vy;
        float dz = vert[g*3+2] - vz;
        float nr = sqrtf(dx*dx + dy*dy + dz*dz);
        float inv = 1.0f / fmaxf(nr, 1e-12f);
        tt[n] = (dx*sx + dy*sy + dz*sz) * inv;
        mx = fmaxf(mx, tt[n]);
    }
    float s = 0.0f;
    #pragma unroll
    for (int n = 0; n < NN; n++){ tt[n] = expf(tt[n] - mx); s += tt[n]; }
    float inv = 1.0f / s;
    float* dst = iw + (size_t)t * NN;
    #pragma unroll
    for (int q = 0; q < 4; q++){
        float4 v = make_float4(tt[q*4]*inv, tt[q*4+1]*inv, tt[q*4+2]*inv, tt[q*4+3]*inv);
        *(float4*)(dst + q*4) = v;
    }
}

// ---------------- Kernel 2: W_eff -> B matrix [n=(d*12+r)][kk=k*768+c*12+a] bf16 ----------------
__global__ __launch_bounds__(256) void k_beff(const float* __restrict__ W,
                                              const int* __restrict__ idx_map,
                                              const int* __restrict__ tiv,   // (12,13)
                                              const int* __restrict__ tir,   // (12,12)
                                              unsigned short* __restrict__ Bm)
{
    int t = blockIdx.x * 256 + threadIdx.x;   // < 64*12*13*64 = 638976
    int c = t & 63;
    int rest = t >> 6;          // < 9984
    int k = rest % KN;
    int rest2 = rest / KN;      // < 768
    int r = rest2 % AN;
    int d = rest2 / AN;
    int tv = tiv[r*KN + k];
    const float* wrow = W + (size_t)((d << 6) + c) * 36;
    s16x4 v0, v1, v2;
    #pragma unroll
    for (int a = 0; a < AN; a++){
        int s = idx_map[tv*AN + tir[r*AN + a]];
        unsigned short h = f2bf(wrow[s]);
        if (a < 4) v0[a] = (short)h;
        else if (a < 8) v1[a-4] = (short)h;
        else v2[a-8] = (short)h;
    }
    unsigned short* dst = Bm + ((size_t)(d*AN + r) * KDIM + k*768 + c*AN);
    s16x4* d4 = (s16x4*)dst;
    d4[0] = v0; d4[1] = v1; d4[2] = v2;
}

// ---------------- Kernel 3: new_feat -> A matrix [m][kk=k*768+c*12+a] bf16 ----------------
// 2 waves per point (k-halves), lane = channel c. 72 fp32 accumulators per lane.
__global__ __launch_bounds__(256) void k_newfeat(const int* __restrict__ nbr,
                                                 const float* __restrict__ fm,
                                                 const float* __restrict__ iw,
                                                 unsigned short* __restrict__ Am)
{
    __shared__ int   nbs_s[2][NN];
    __shared__ float iwT_s[2][NN][AN];      // [point-in-block][n][k]
    int t = threadIdx.x;
    int w = t >> 6, lane = t & 63;
    int pw = w >> 1, khalf = w & 1;
    int m = blockIdx.x * 2 + pw;            // point id < 4096
    int b = m >> 10, p = m & 1023;
    const float* fmb = fm + (size_t)b * (C1N * PN * AN);

    if (khalf == 0){
        if (lane < NN) nbs_s[pw][lane] = nbr[m*NN + lane];
        #pragma unroll
        for (int i = 0; i < 3; i++){
            int idx = lane + i*64;              // < 192
            int a = idx >> 4, n = idx & 15;     // iw layout [a][n]
            iwT_s[pw][n][a] = iw[(size_t)m * (AN*NN) + idx];
        }
    }
    __syncthreads();

    f32x4 acc[6][3];
    #pragma unroll
    for (int k = 0; k < 6; k++)
        #pragma unroll
        for (int q = 0; q < 3; q++) acc[k][q] = (f32x4){0.f,0.f,0.f,0.f};

    const float* crow = fmb + (size_t)lane * (PN * AN);   // fm[b][c=lane][...]
    int kb = khalf * 6;

    #pragma unroll 2
    for (int n = 0; n < NN; n++){
        int pp = nbs_s[pw][n];
        const float* src = crow + pp * AN;
        f32x4 v0 = *(const f32x4*)(src);
        f32x4 v1 = *(const f32x4*)(src + 4);
        f32x4 v2 = *(const f32x4*)(src + 8);
        #pragma unroll
        for (int k = 0; k < 6; k++){
            float wv = iwT_s[pw][n][kb + k];
            acc[k][0] += v0 * wv;
            acc[k][1] += v1 * wv;
            acc[k][2] += v2 * wv;
        }
    }

    unsigned short* dst = Am + (size_t)m * KDIM + lane * AN;
    #pragma unroll
    for (int k = 0; k < 6; k++){
        s16x4 h0, h1, h2;
        #pragma unroll
        for (int j = 0; j < 4; j++){
            h0[j] = (short)f2bf(acc[k][0][j]);
            h1[j] = (short)f2bf(acc[k][1][j]);
            h2[j] = (short)f2bf(acc[k][2][j]);
        }
        s16x4* o = (s16x4*)(dst + (kb + k)*768);
        o[0] = h0; o[1] = h1; o[2] = h2;
    }
    if (khalf){
        const float* own = crow + (size_t)p * AN;
        f32x4 s0 = *(const f32x4*)(own);
        f32x4 s1 = *(const f32x4*)(own + 4);
        f32x4 s2 = *(const f32x4*)(own + 8);
        s16x4 h0, h1, h2;
        #pragma unroll
        for (int j = 0; j < 4; j++){
            h0[j] = (short)f2bf(s0[j]);
            h1[j] = (short)f2bf(s1[j]);
            h2[j] = (short)f2bf(s2[j]);
        }
        s16x4* o = (s16x4*)(dst + 12*768);
        o[0] = h0; o[1] = h1; o[2] = h2;
    }
}

// ---------------- Kernel 4: GEMM (m97 structure, BK=64, T2 source-side swizzle) ----------------
// 128x128 tile, 4 waves (2x2, 64x64 each), 16x16x32 bf16, global_load_lds(16), split-K
// LDS [row][64] row-major (128B stride). Swizzle: 16B-chunk cc stored at cc^(row&7);
// applied on the GLOBAL source (rule #21) + on the ds_read address. Involution.
__global__ __launch_bounds__(256) void k_gemm(const unsigned short* __restrict__ Am,
                                              const unsigned short* __restrict__ Bm,
                                              float* __restrict__ part,
                                              float* __restrict__ out,
                                              int klen, int nsplit)
{
    __shared__ unsigned short Al[128*BK];   // 16 KB, linear dest (global_load_lds)
    __shared__ unsigned short Bl[128*BK];
    int t = threadIdx.x;
    int lane = t & 63, w = t >> 6;
    int wr = w >> 1, wc = w & 1;
    int l15 = lane & 15;
    int kofs = (lane >> 4) * 8;             // elems within 32-wide k-half
    int m0 = blockIdx.x * 128, n0 = blockIdx.y * 128;
    int kbase = blockIdx.z * klen;

    // staging chunks: g = i*256 + w*64 + lane; row=g>>3, ch=g&7 (16B chunks of 128B row)
    const unsigned short* gA[4];
    const unsigned short* gB[4];
    unsigned short* lA[4];
    unsigned short* lB[4];
    #pragma unroll
    for (int i = 0; i < 4; i++){
        int g = i*256 + w*64 + lane;
        int row = g >> 3, ch = g & 7;
        int sch = ch ^ (row & 7);           // pre-swizzled source chunk
        gA[i] = Am + (size_t)(m0 + row) * KDIM + kbase + sch*8;
        gB[i] = Bm + (size_t)(n0 + row) * KDIM + kbase + sch*8;
        lA[i] = &Al[(size_t)(i*256 + w*64) * 8];
        lB[i] = &Bl[(size_t)(i*256 + w*64) * 8];
    }

    f32x4 acc[4][4] = {};

    for (int kk = 0; kk < klen; kk += BK){
        #pragma unroll
        for (int i = 0; i < 4; i++) gload16(gA[i] + kk, lA[i]);
        #pragma unroll
        for (int i = 0; i < 4; i++) gload16(gB[i] + kk, lB[i]);
        __syncthreads();                       // drains vmcnt -> tile ready
        #pragma unroll
        for (int kh = 0; kh < 2; kh++){
            int cc = kh*4 + (kofs >> 3);       // 16B chunk index 0..7
            short8 af[4], bf[4];
            #pragma unroll
            for (int i = 0; i < 4; i++){
                int ra = wr*64 + i*16 + l15;
                af[i] = *(const short8*)&Al[ra*BK + ((cc ^ (ra & 7)) * 8)];
                int rb = wc*64 + i*16 + l15;
                bf[i] = *(const short8*)&Bl[rb*BK + ((cc ^ (rb & 7)) * 8)];
            }
            #pragma unroll
            for (int i = 0; i < 4; i++){
                #pragma unroll
                for (int j = 0; j < 4; j++)
                    acc[i][j] = __builtin_amdgcn_mfma_f32_16x16x32_bf16(af[i], bf[j], acc[i][j], 0, 0, 0);
            }
        }
        __syncthreads();
    }

    // epilogue: C/D layout col=lane&15, row=(lane>>4)*4+q  [m89-verified]
    if (nsplit > 1){
        float* pp = part + (size_t)blockIdx.z * ((size_t)MDIM * NDIM);
        #pragma unroll
        for (int i = 0; i < 4; i++){
            #pragma unroll
            for (int j = 0; j < 4; j++){
                int col = n0 + wc*64 + j*16 + l15;
                #pragma unroll
                for (int q = 0; q < 4; q++){
                    int row = m0 + wr*64 + i*16 + (lane >> 4)*4 + q;
                    pp[(size_t)row * NDIM + col] = acc[i][j][q];
                }
            }
        }
    } else {
        #pragma unroll
        for (int i = 0; i < 4; i++){
            #pragma unroll
            for (int j = 0; j < 4; j++){
                int col = n0 + wc*64 + j*16 + l15;
                int d = col / AN, r = col - d*AN;
                #pragma unroll
                for (int q = 0; q < 4; q++){
                    int row = m0 + wr*64 + i*16 + (lane >> 4)*4 + q;
                    int b = row >> 10, pp2 = row & 1023;
                    out[((size_t)((b << 6) + d) * PN + pp2) * AN + r] = acc[i][j][q];
                }
            }
        }
    }
}

// ---------------- Kernel 5: split-K reduce + scatter to bdpr ----------------
__global__ __launch_bounds__(256) void k_reduce(const float* __restrict__ part,
                                                float* __restrict__ out, int nsplit)
{
    int t = blockIdx.x * 256 + threadIdx.x;        // per float4: MDIM*NDIM/4
    if (t >= MDIM * (NDIM/4)) return;
    int m = t / (NDIM/4);
    int n4 = (t - m * (NDIM/4)) * 4;
    f32x4 s = {};
    for (int z = 0; z < nsplit; z++){
        f32x4 v = *(const f32x4*)(part + (size_t)z * ((size_t)MDIM * NDIM) + (size_t)m * NDIM + n4);
        s += v;
    }
    int b = m >> 10, p = m & 1023;
    int d = n4 / AN, r = n4 - d*AN;    // r in {0,4,8}: never crosses d within 4
    *(f32x4*)(out + ((size_t)((b << 6) + d) * PN + p) * AN + r) = s;
}

extern "C" void kernel_launch(void* const* d_in, const int* in_sizes, int n_in,
                              void* d_out, int out_size, void* d_ws, size_t ws_size,
                              hipStream_t stream)
{
    const int*   nbr     = (const int*)  d_in[0];
    const float* vert    = (const float*)d_in[1];
    const float* fm      = (const float*)d_in[2];
    const float* W       = (const float*)d_in[3];
    const float* vs      = (const float*)d_in[4];
    const int*   idx_map = (const int*)  d_in[5];
    const int*   tiv     = (const int*)  d_in[6];
    const int*   tir     = (const int*)  d_in[7];
    float* out = (float*)d_out;

    char* ws = (char*)d_ws;
    float*          iw   = (float*)ws;                                  // 3,145,728 B
    unsigned short* Bm   = (unsigned short*)(ws + 3145728);             // 15,335,424 B
    unsigned short* Am   = (unsigned short*)(ws + 18481152);            // 81,788,928 B
    float*          part = (float*)(ws + 100270080);

    long long avail = (long long)ws_size - 100270080LL;
    int nsplit = (int)(avail / 12582912LL);
    if (nsplit > 4) nsplit = 4;
    if (nsplit < 1) nsplit = 1;
    int klen = KDIM / nsplit;    // nsplit in {1,2,3,4}: klen always a multiple of 64

    k_interw <<<(MDIM*AN)/256, 256, 0, stream>>>(nbr, vert, vs, iw);
    k_beff   <<<(C2N*AN*C1N*KN)/256, 256, 0, stream>>>(W, idx_map, tiv, tir, Bm);
    k_newfeat<<<MDIM/2, 256, 0, stream>>>(nbr, fm, iw, Am);
    dim3 g(MDIM/128, NDIM/128, nsplit);
    k_gemm   <<<g, 256, 0, stream>>>(Am, Bm, part, out, klen, nsplit);
    if (nsplit > 1)
        k_reduce<<<(MDIM*(NDIM/4))/256, 256, 0, stream>>>(part, out, nsplit);
}

// Round 5
// 170.041 us; speedup vs baseline: 1.1443x; 1.1443x over previous
//
#include <hip/hip_runtime.h>
#include <hip/hip_bf16.h>

typedef __attribute__((ext_vector_type(8))) short short8;
typedef __attribute__((ext_vector_type(4))) short s16x4;
typedef __attribute__((ext_vector_type(4))) float f32x4;

#define BN 4
#define PN 1024
#define NN 16
#define C1N 64
#define C2N 64
#define KN 13
#define AN 12
#define KDIM 9984   // C1N*KN*AN, kk = k*768 + c*12 + a
#define NDIM 768    // C2N*AN
#define MDIM 4096   // BN*PN
#define BK 64

__device__ inline unsigned short f2bf(float x){
    unsigned int u = __float_as_uint(x);
    unsigned int r = (u + 0x7fffu + ((u >> 16) & 1u)) >> 16;
    return (unsigned short)r;
}

// async global->LDS, 16B per lane. LDS dest = wave-uniform base + lane*16.
__device__ __forceinline__ void gload16(const unsigned short* g, unsigned short* l){
    __builtin_amdgcn_global_load_lds(
        (const __attribute__((address_space(1))) unsigned int*)(unsigned long long)(uintptr_t)g,
        (__attribute__((address_space(3))) unsigned int*)(unsigned int)(uintptr_t)l,
        16, 0, 0);
}

// ---------------- Kernel 1: inter_w softmax weights ----------------
__global__ __launch_bounds__(256) void k_interw(const int* __restrict__ nbr,
                                                const float* __restrict__ vert,
                                                const float* __restrict__ vs,
                                                float* __restrict__ iw)
{
    int t = blockIdx.x * 256 + threadIdx.x;      // < 49152
    if (t >= MDIM * AN) return;
    int pt = t / AN, a = t - pt * AN;
    int b = pt >> 10;
    float sx = vs[a*3+0], sy = vs[a*3+1], sz = vs[a*3+2];
    float sn = sqrtf(sx*sx + sy*sy + sz*sz);
    float si = 1.0f / fmaxf(sn, 1e-12f);
    sx *= si; sy *= si; sz *= si;
    float vx = vert[pt*3+0], vy = vert[pt*3+1], vz = vert[pt*3+2];
    float tt[NN];
    float mx = -1e30f;
    #pragma unroll
    for (int n = 0; n < NN; n++){
        int g = (b << 10) + nbr[pt*NN + n];
        float dx = vert[g*3+0] - vx;
        float dy = vert[g*3+1] - vy;
        float dz = vert[g*3+2] - vz;
        float nr = sqrtf(dx*dx + dy*dy + dz*dz);
        float inv = 1.0f / fmaxf(nr, 1e-12f);
        tt[n] = (dx*sx + dy*sy + dz*sz) * inv;
        mx = fmaxf(mx, tt[n]);
    }
    float s = 0.0f;
    #pragma unroll
    for (int n = 0; n < NN; n++){ tt[n] = expf(tt[n] - mx); s += tt[n]; }
    float inv = 1.0f / s;
    float* dst = iw + (size_t)t * NN;
    #pragma unroll
    for (int q = 0; q < 4; q++){
        float4 v = make_float4(tt[q*4]*inv, tt[q*4+1]*inv, tt[q*4+2]*inv, tt[q*4+3]*inv);
        *(float4*)(dst + q*4) = v;
    }
}

// ---------------- Kernel 2: W_eff -> B matrix [n=(d*12+r)][kk=k*768+c*12+a] bf16 ----------------
__global__ __launch_bounds__(256) void k_beff(const float* __restrict__ W,
                                              const int* __restrict__ idx_map,
                                              const int* __restrict__ tiv,   // (12,13)
                                              const int* __restrict__ tir,   // (12,12)
                                              unsigned short* __restrict__ Bm)
{
    int t = blockIdx.x * 256 + threadIdx.x;   // < 64*12*13*64 = 638976
    int c = t & 63;
    int rest = t >> 6;          // < 9984
    int k = rest % KN;
    int rest2 = rest / KN;      // < 768
    int r = rest2 % AN;
    int d = rest2 / AN;
    int tv = tiv[r*KN + k];
    const float* wrow = W + (size_t)((d << 6) + c) * 36;
    s16x4 v0, v1, v2;
    #pragma unroll
    for (int a = 0; a < AN; a++){
        int s = idx_map[tv*AN + tir[r*AN + a]];
        unsigned short h = f2bf(wrow[s]);
        if (a < 4) v0[a] = (short)h;
        else if (a < 8) v1[a-4] = (short)h;
        else v2[a-8] = (short)h;
    }
    unsigned short* dst = Bm + ((size_t)(d*AN + r) * KDIM + k*768 + c*AN);
    s16x4* d4 = (s16x4*)dst;
    d4[0] = v0; d4[1] = v1; d4[2] = v2;
}

// ---------------- Kernel 3: new_feat -> A matrix [m][kk=k*768+c*12+a] bf16 ----------------
// wave per point, lane = channel c. 144 fp32 accumulators per lane. (R3 version)
__global__ __launch_bounds__(256) void k_newfeat(const int* __restrict__ nbr,
                                                 const float* __restrict__ fm,
                                                 const float* __restrict__ iw,
                                                 unsigned short* __restrict__ Am)
{
    __shared__ int   nbs_s[4][NN];
    __shared__ float iwT_s[4][NN][AN];      // [wave][n][k]
    int t = threadIdx.x;
    int w = t >> 6, lane = t & 63;
    int m = blockIdx.x * 4 + w;             // point id < 4096
    int b = m >> 10, p = m & 1023;
    const float* fmb = fm + (size_t)b * (C1N * PN * AN);

    if (lane < NN) nbs_s[w][lane] = nbr[m*NN + lane];
    #pragma unroll
    for (int i = 0; i < 3; i++){
        int idx = lane + i*64;              // < 192
        int a = idx >> 4, n = idx & 15;     // iw layout [a][n]
        iwT_s[w][n][a] = iw[(size_t)m * (AN*NN) + idx];
    }
    __syncthreads();

    f32x4 acc[12][3];
    #pragma unroll
    for (int k = 0; k < 12; k++){
        #pragma unroll
        for (int q = 0; q < 3; q++) acc[k][q] = (f32x4){0.f,0.f,0.f,0.f};
    }

    const float* crow = fmb + (size_t)lane * (PN * AN);   // fm[b][c=lane][...]

    #pragma unroll 2
    for (int n = 0; n < NN; n++){
        int pp = nbs_s[w][n];
        const float* src = crow + pp * AN;
        f32x4 v0 = *(const f32x4*)(src);
        f32x4 v1 = *(const f32x4*)(src + 4);
        f32x4 v2 = *(const f32x4*)(src + 8);
        f32x4 w0 = *(const f32x4*)&iwT_s[w][n][0];
        f32x4 w1 = *(const f32x4*)&iwT_s[w][n][4];
        f32x4 w2 = *(const f32x4*)&iwT_s[w][n][8];
        float wk[12] = {w0[0],w0[1],w0[2],w0[3],
                        w1[0],w1[1],w1[2],w1[3],
                        w2[0],w2[1],w2[2],w2[3]};
        #pragma unroll
        for (int k = 0; k < 12; k++){
            acc[k][0] += v0 * wk[k];
            acc[k][1] += v1 * wk[k];
            acc[k][2] += v2 * wk[k];
        }
    }

    // own features (k = 12 slice)
    const float* own = crow + (size_t)p * AN;
    f32x4 s0 = *(const f32x4*)(own);
    f32x4 s1 = *(const f32x4*)(own + 4);
    f32x4 s2 = *(const f32x4*)(own + 8);

    unsigned short* dst = Am + (size_t)m * KDIM + lane * AN;
    #pragma unroll
    for (int k = 0; k < 12; k++){
        s16x4 h0, h1, h2;
        #pragma unroll
        for (int j = 0; j < 4; j++){
            h0[j] = (short)f2bf(acc[k][0][j]);
            h1[j] = (short)f2bf(acc[k][1][j]);
            h2[j] = (short)f2bf(acc[k][2][j]);
        }
        s16x4* o = (s16x4*)(dst + k*768);
        o[0] = h0; o[1] = h1; o[2] = h2;
    }
    {
        s16x4 h0, h1, h2;
        #pragma unroll
        for (int j = 0; j < 4; j++){
            h0[j] = (short)f2bf(s0[j]);
            h1[j] = (short)f2bf(s1[j]);
            h2[j] = (short)f2bf(s2[j]);
        }
        s16x4* o = (s16x4*)(dst + 12*768);
        o[0] = h0; o[1] = h1; o[2] = h2;
    }
}

// ---------------- Kernel 4: GEMM, double-buffered pipeline (T3 minimal 2-phase) ----------------
// 128x128 tile, 4 waves (2x2, 64x64 each), 16x16x32 bf16, BK=64, global_load_lds(16),
// T2 source-side chunk swizzle (rule #21: linear dest + inv-swz source + swz read).
// Pipeline: issue next-tile loads FIRST, compute current, single barrier per K-step
// (its vmcnt(0) drain lands after the compute phase -> load latency hidden).
__global__ __launch_bounds__(256) void k_gemm(const unsigned short* __restrict__ Am,
                                              const unsigned short* __restrict__ Bm,
                                              float* __restrict__ part,
                                              float* __restrict__ out,
                                              int klen, int nsplit)
{
    __shared__ unsigned short Al[2][128*BK];   // 2 x 16 KB
    __shared__ unsigned short Bl[2][128*BK];
    int t = threadIdx.x;
    int lane = t & 63, w = t >> 6;
    int wr = w >> 1, wc = w & 1;
    int l15 = lane & 15;
    int kofs = (lane >> 4) * 8;             // elems within 32-wide k-half
    int m0 = blockIdx.x * 128, n0 = blockIdx.y * 128;
    int kbase = blockIdx.z * klen;

    // staging chunks: g = i*256 + w*64 + lane; row=g>>3, ch=g&7 (16B chunks of 128B row)
    const unsigned short* gA[4];
    const unsigned short* gB[4];
    int lofs[4];
    #pragma unroll
    for (int i = 0; i < 4; i++){
        int g = i*256 + w*64 + lane;
        int row = g >> 3, ch = g & 7;
        int sch = ch ^ (row & 7);           // pre-swizzled source chunk
        gA[i] = Am + (size_t)(m0 + row) * KDIM + kbase + sch*8;
        gB[i] = Bm + (size_t)(n0 + row) * KDIM + kbase + sch*8;
        lofs[i] = (i*256 + w*64) * 8;
    }

    f32x4 acc[4][4] = {};
    int nt = klen / BK;

    // prologue: stage tile 0 into buffer 0
    #pragma unroll
    for (int i = 0; i < 4; i++) gload16(gA[i], &Al[0][lofs[i]]);
    #pragma unroll
    for (int i = 0; i < 4; i++) gload16(gB[i], &Bl[0][lofs[i]]);
    __syncthreads();

    for (int ti = 0; ti < nt; ++ti){
        int cur = ti & 1;
        if (ti + 1 < nt){
            int kk = (ti + 1) * BK;
            #pragma unroll
            for (int i = 0; i < 4; i++) gload16(gA[i] + kk, &Al[cur^1][lofs[i]]);
            #pragma unroll
            for (int i = 0; i < 4; i++) gload16(gB[i] + kk, &Bl[cur^1][lofs[i]]);
        }
        #pragma unroll
        for (int kh = 0; kh < 2; kh++){
            int cc = kh*4 + (kofs >> 3);       // 16B chunk index 0..7
            short8 af[4], bf[4];
            #pragma unroll
            for (int i = 0; i < 4; i++){
                int ra = wr*64 + i*16 + l15;
                af[i] = *(const short8*)&Al[cur][ra*BK + ((cc ^ (ra & 7)) * 8)];
                int rb = wc*64 + i*16 + l15;
                bf[i] = *(const short8*)&Bl[cur][rb*BK + ((cc ^ (rb & 7)) * 8)];
            }
            #pragma unroll
            for (int i = 0; i < 4; i++){
                #pragma unroll
                for (int j = 0; j < 4; j++)
                    acc[i][j] = __builtin_amdgcn_mfma_f32_16x16x32_bf16(af[i], bf[j], acc[i][j], 0, 0, 0);
            }
        }
        __syncthreads();   // drains my next-tile loads (after compute) + LDS RAW/WAR
    }

    // epilogue: C/D layout col=lane&15, row=(lane>>4)*4+q  [m89-verified]
    if (nsplit > 1){
        float* pp = part + (size_t)blockIdx.z * ((size_t)MDIM * NDIM);
        #pragma unroll
        for (int i = 0; i < 4; i++){
            #pragma unroll
            for (int j = 0; j < 4; j++){
                int col = n0 + wc*64 + j*16 + l15;
                #pragma unroll
                for (int q = 0; q < 4; q++){
                    int row = m0 + wr*64 + i*16 + (lane >> 4)*4 + q;
                    pp[(size_t)row * NDIM + col] = acc[i][j][q];
                }
            }
        }
    } else {
        #pragma unroll
        for (int i = 0; i < 4; i++){
            #pragma unroll
            for (int j = 0; j < 4; j++){
                int col = n0 + wc*64 + j*16 + l15;
                int d = col / AN, r = col - d*AN;
                #pragma unroll
                for (int q = 0; q < 4; q++){
                    int row = m0 + wr*64 + i*16 + (lane >> 4)*4 + q;
                    int b = row >> 10, pp2 = row & 1023;
                    out[((size_t)((b << 6) + d) * PN + pp2) * AN + r] = acc[i][j][q];
                }
            }
        }
    }
}

// ---------------- Kernel 5: split-K reduce + scatter to bdpr ----------------
__global__ __launch_bounds__(256) void k_reduce(const float* __restrict__ part,
                                                float* __restrict__ out, int nsplit)
{
    int t = blockIdx.x * 256 + threadIdx.x;        // per float4: MDIM*NDIM/4
    if (t >= MDIM * (NDIM/4)) return;
    int m = t / (NDIM/4);
    int n4 = (t - m * (NDIM/4)) * 4;
    f32x4 s = {};
    for (int z = 0; z < nsplit; z++){
        f32x4 v = *(const f32x4*)(part + (size_t)z * ((size_t)MDIM * NDIM) + (size_t)m * NDIM + n4);
        s += v;
    }
    int b = m >> 10, p = m & 1023;
    int d = n4 / AN, r = n4 - d*AN;    // r in {0,4,8}: never crosses d within 4
    *(f32x4*)(out + ((size_t)((b << 6) + d) * PN + p) * AN + r) = s;
}

extern "C" void kernel_launch(void* const* d_in, const int* in_sizes, int n_in,
                              void* d_out, int out_size, void* d_ws, size_t ws_size,
                              hipStream_t stream)
{
    const int*   nbr     = (const int*)  d_in[0];
    const float* vert    = (const float*)d_in[1];
    const float* fm      = (const float*)d_in[2];
    const float* W       = (const float*)d_in[3];
    const float* vs      = (const float*)d_in[4];
    const int*   idx_map = (const int*)  d_in[5];
    const int*   tiv     = (const int*)  d_in[6];
    const int*   tir     = (const int*)  d_in[7];
    float* out = (float*)d_out;

    char* ws = (char*)d_ws;
    float*          iw   = (float*)ws;                                  // 3,145,728 B
    unsigned short* Bm   = (unsigned short*)(ws + 3145728);             // 15,335,424 B
    unsigned short* Am   = (unsigned short*)(ws + 18481152);            // 81,788,928 B
    float*          part = (float*)(ws + 100270080);

    // split-K: valid values keep klen a multiple of BK=64 (KDIM = 156*64)
    long long avail = (long long)ws_size - 100270080LL;
    int maxs = (int)(avail / 12582912LL);
    int nsplit = (maxs >= 6) ? 6 : (maxs >= 4) ? 4 : (maxs >= 3) ? 3 : (maxs >= 2) ? 2 : 1;
    int klen = KDIM / nsplit;

    k_interw <<<(MDIM*AN)/256, 256, 0, stream>>>(nbr, vert, vs, iw);
    k_beff   <<<(C2N*AN*C1N*KN)/256, 256, 0, stream>>>(W, idx_map, tiv, tir, Bm);
    k_newfeat<<<MDIM/4, 256, 0, stream>>>(nbr, fm, iw, Am);
    dim3 g(MDIM/128, NDIM/128, nsplit);
    k_gemm   <<<g, 256, 0, stream>>>(Am, Bm, part, out, klen, nsplit);
    if (nsplit > 1)
        k_reduce<<<(MDIM*(NDIM/4))/256, 256, 0, stream>>>(part, out, nsplit);
}

// Round 6
// 148.724 us; speedup vs baseline: 1.3083x; 1.1433x over previous
//
#include <hip/hip_runtime.h>
#include <hip/hip_bf16.h>

typedef __attribute__((ext_vector_type(8))) short short8;
typedef __attribute__((ext_vector_type(4))) short s16x4;
typedef __attribute__((ext_vector_type(4))) float f32x4;

#define BN 4
#define PN 1024
#define NN 16
#define C1N 64
#define C2N 64
#define KN 13
#define AN 12
#define KDIM 9984   // C1N*KN*AN, kk = k*768 + c*12 + a  (k=12 slice at 9216+)
#define NDIM 768    // C2N*AN
#define MDIM 4096   // BN*PN
#define BK 64

__device__ inline unsigned short f2bf(float x){
    unsigned int u = __float_as_uint(x);
    unsigned int r = (u + 0x7fffu + ((u >> 16) & 1u)) >> 16;
    return (unsigned short)r;
}
__device__ inline f32x4 bf4_to_f(s16x4 h){
    f32x4 r;
    r[0] = __uint_as_float(((unsigned)(unsigned short)h[0]) << 16);
    r[1] = __uint_as_float(((unsigned)(unsigned short)h[1]) << 16);
    r[2] = __uint_as_float(((unsigned)(unsigned short)h[2]) << 16);
    r[3] = __uint_as_float(((unsigned)(unsigned short)h[3]) << 16);
    return r;
}

// async global->LDS, 16B per lane. LDS dest = wave-uniform base + lane*16.
__device__ __forceinline__ void gload16(const unsigned short* g, unsigned short* l){
    __builtin_amdgcn_global_load_lds(
        (const __attribute__((address_space(1))) unsigned int*)(unsigned long long)(uintptr_t)g,
        (__attribute__((address_space(3))) unsigned int*)(unsigned int)(uintptr_t)l,
        16, 0, 0);
}

// ---------------- Kernel 1: inter_w softmax weights ----------------
__global__ __launch_bounds__(256) void k_interw(const int* __restrict__ nbr,
                                                const float* __restrict__ vert,
                                                const float* __restrict__ vs,
                                                float* __restrict__ iw)
{
    int t = blockIdx.x * 256 + threadIdx.x;      // < 49152
    if (t >= MDIM * AN) return;
    int pt = t / AN, a = t - pt * AN;
    int b = pt >> 10;
    float sx = vs[a*3+0], sy = vs[a*3+1], sz = vs[a*3+2];
    float sn = sqrtf(sx*sx + sy*sy + sz*sz);
    float si = 1.0f / fmaxf(sn, 1e-12f);
    sx *= si; sy *= si; sz *= si;
    float vx = vert[pt*3+0], vy = vert[pt*3+1], vz = vert[pt*3+2];
    float tt[NN];
    float mx = -1e30f;
    #pragma unroll
    for (int n = 0; n < NN; n++){
        int g = (b << 10) + nbr[pt*NN + n];
        float dx = vert[g*3+0] - vx;
        float dy = vert[g*3+1] - vy;
        float dz = vert[g*3+2] - vz;
        float nr = sqrtf(dx*dx + dy*dy + dz*dz);
        float inv = 1.0f / fmaxf(nr, 1e-12f);
        tt[n] = (dx*sx + dy*sy + dz*sz) * inv;
        mx = fmaxf(mx, tt[n]);
    }
    float s = 0.0f;
    #pragma unroll
    for (int n = 0; n < NN; n++){ tt[n] = expf(tt[n] - mx); s += tt[n]; }
    float inv = 1.0f / s;
    float* dst = iw + (size_t)t * NN;
    #pragma unroll
    for (int q = 0; q < 4; q++){
        float4 v = make_float4(tt[q*4]*inv, tt[q*4+1]*inv, tt[q*4+2]*inv, tt[q*4+3]*inv);
        *(float4*)(dst + q*4) = v;
    }
}

// ---------------- Kernel 2: W_eff -> B matrix [n=(d*12+r)][kk=k*768+c*12+a] bf16 ----------------
__global__ __launch_bounds__(256) void k_beff(const float* __restrict__ W,
                                              const int* __restrict__ idx_map,
                                              const int* __restrict__ tiv,   // (12,13)
                                              const int* __restrict__ tir,   // (12,12)
                                              unsigned short* __restrict__ Bm)
{
    int t = blockIdx.x * 256 + threadIdx.x;   // < 64*12*13*64 = 638976
    int c = t & 63;
    int rest = t >> 6;          // < 9984
    int k = rest % KN;
    int rest2 = rest / KN;      // < 768
    int r = rest2 % AN;
    int d = rest2 / AN;
    int tv = tiv[r*KN + k];
    const float* wrow = W + (size_t)((d << 6) + c) * 36;
    s16x4 v0, v1, v2;
    #pragma unroll
    for (int a = 0; a < AN; a++){
        int s = idx_map[tv*AN + tir[r*AN + a]];
        unsigned short h = f2bf(wrow[s]);
        if (a < 4) v0[a] = (short)h;
        else if (a < 8) v1[a-4] = (short)h;
        else v2[a-8] = (short)h;
    }
    unsigned short* dst = Bm + ((size_t)(d*AN + r) * KDIM + k*768 + c*AN);
    s16x4* d4 = (s16x4*)dst;
    d4[0] = v0; d4[1] = v1; d4[2] = v2;
}

// ---------------- Kernel 2b: fm -> bf16 own-feature slice Am[m][9216 + c*12 + a] ----------------
// coalesced fm reads (4KB/wave); scattered 8B writes absorbed by L2 (6.3MB region)
__global__ __launch_bounds__(256) void k_tr(const float* __restrict__ fm,
                                            unsigned short* __restrict__ Am)
{
    int t = blockIdx.x * 256 + threadIdx.x;     // < BN*C1N*PN*3 = 786432
    int a4 = t % 3;
    int rest = t / 3;                            // (b*64 + c)*1024 + p
    int p = rest & 1023;
    int bc = rest >> 10;
    int c = bc & 63, b = bc >> 6;
    float4 v = *(const float4*)(fm + (size_t)rest * 12 + a4*4);
    s16x4 h;
    h[0] = (short)f2bf(v.x); h[1] = (short)f2bf(v.y);
    h[2] = (short)f2bf(v.z); h[3] = (short)f2bf(v.w);
    int m = (b << 10) + p;
    *(s16x4*)(Am + (size_t)m * KDIM + 9216 + c*12 + a4*4) = h;
}

// ---------------- Kernel 3: new_feat k=0..11 -> Am[m][k*768+c*12+a] ----------------
// 2 waves per point (k-halves), lane = channel c. Gathers = contiguous 1536B bf16 rows
// from the k=12 slice (written by k_tr). acc 72 VGPR -> ~4 waves/SIMD.
__global__ __launch_bounds__(256) void k_newfeat(const int* __restrict__ nbr,
                                                 const float* __restrict__ iw,
                                                 unsigned short* Am)
{
    __shared__ int   nbs_s[2][NN];
    __shared__ float iwT_s[2][NN][AN];      // [point-in-block][n][k]
    int t = threadIdx.x;
    int w = t >> 6, lane = t & 63;
    int pw = w >> 1, khalf = w & 1;
    int m = blockIdx.x * 2 + pw;            // point id < 4096
    int b = m >> 10;

    if (khalf == 0){
        if (lane < NN) nbs_s[pw][lane] = nbr[m*NN + lane];
        #pragma unroll
        for (int i = 0; i < 3; i++){
            int idx = lane + i*64;              // < 192
            int a = idx >> 4, n = idx & 15;     // iw layout [a][n]
            iwT_s[pw][n][a] = iw[(size_t)m * (AN*NN) + idx];
        }
    }
    __syncthreads();

    f32x4 acc[6][3];
    #pragma unroll
    for (int k = 0; k < 6; k++)
        #pragma unroll
        for (int q = 0; q < 3; q++) acc[k][q] = (f32x4){0.f,0.f,0.f,0.f};

    int kb = khalf * 6;
    const unsigned short* slice = Am + 9216 + (size_t)lane * AN;

    #pragma unroll 2
    for (int n = 0; n < NN; n++){
        int mn = (b << 10) + nbs_s[pw][n];
        const unsigned short* src = slice + (size_t)mn * KDIM;
        s16x4 u0 = *(const s16x4*)(src);
        s16x4 u1 = *(const s16x4*)(src + 4);
        s16x4 u2 = *(const s16x4*)(src + 8);
        f32x4 v0 = bf4_to_f(u0), v1 = bf4_to_f(u1), v2 = bf4_to_f(u2);
        #pragma unroll
        for (int k = 0; k < 6; k++){
            float wv = iwT_s[pw][n][kb + k];
            acc[k][0] += v0 * wv;
            acc[k][1] += v1 * wv;
            acc[k][2] += v2 * wv;
        }
    }

    unsigned short* dst = Am + (size_t)m * KDIM + lane * AN;
    #pragma unroll
    for (int k = 0; k < 6; k++){
        s16x4 h0, h1, h2;
        #pragma unroll
        for (int j = 0; j < 4; j++){
            h0[j] = (short)f2bf(acc[k][0][j]);
            h1[j] = (short)f2bf(acc[k][1][j]);
            h2[j] = (short)f2bf(acc[k][2][j]);
        }
        s16x4* o = (s16x4*)(dst + (kb + k)*768);
        o[0] = h0; o[1] = h1; o[2] = h2;
    }
}

// ---------------- Kernel 4: GEMM, double-buffered, T2 swizzle, T1 XCD remap ----------------
// 128x128 tile, 4 waves (2x2, 64x64 each), 16x16x32 bf16, BK=64, global_load_lds(16), split-K.
// XCD remap: linear bid (x fastest) % 8 = XCD; give each XCD 4 consecutive bx * all 6 by
// -> A working set 4 panels ~1.7MB resides in per-XCD L2, fetched from HBM ~once.
__global__ __launch_bounds__(256) void k_gemm(const unsigned short* __restrict__ Am,
                                              const unsigned short* __restrict__ Bm,
                                              float* __restrict__ part,
                                              float* __restrict__ out,
                                              int klen, int nsplit)
{
    __shared__ unsigned short Al[2][128*BK];   // 2 x 16 KB
    __shared__ unsigned short Bl[2][128*BK];
    int t = threadIdx.x;
    int lane = t & 63, w = t >> 6;
    int wr = w >> 1, wc = w & 1;
    int l15 = lane & 15;
    int kofs = (lane >> 4) * 8;
    // XCD-aware remap of the 32x6 (x,y) grid (192 = 8 XCDs x 24)
    int bid = (int)blockIdx.x + 32 * (int)blockIdx.y;
    int rb  = (bid & 7) * 24 + (bid >> 3);
    int bx = rb / 6, by = rb - 6 * (rb / 6);
    int m0 = bx * 128, n0 = by * 128;
    int kbase = blockIdx.z * klen;

    const unsigned short* gA[4];
    const unsigned short* gB[4];
    int lofs[4];
    #pragma unroll
    for (int i = 0; i < 4; i++){
        int g = i*256 + w*64 + lane;
        int row = g >> 3, ch = g & 7;
        int sch = ch ^ (row & 7);           // pre-swizzled source chunk (involution)
        gA[i] = Am + (size_t)(m0 + row) * KDIM + kbase + sch*8;
        gB[i] = Bm + (size_t)(n0 + row) * KDIM + kbase + sch*8;
        lofs[i] = (i*256 + w*64) * 8;
    }

    f32x4 acc[4][4] = {};
    int nt = klen / BK;

    #pragma unroll
    for (int i = 0; i < 4; i++) gload16(gA[i], &Al[0][lofs[i]]);
    #pragma unroll
    for (int i = 0; i < 4; i++) gload16(gB[i], &Bl[0][lofs[i]]);
    __syncthreads();

    for (int ti = 0; ti < nt; ++ti){
        int cur = ti & 1;
        if (ti + 1 < nt){
            int kk = (ti + 1) * BK;
            #pragma unroll
            for (int i = 0; i < 4; i++) gload16(gA[i] + kk, &Al[cur^1][lofs[i]]);
            #pragma unroll
            for (int i = 0; i < 4; i++) gload16(gB[i] + kk, &Bl[cur^1][lofs[i]]);
        }
        #pragma unroll
        for (int kh = 0; kh < 2; kh++){
            int cc = kh*4 + (kofs >> 3);
            short8 af[4], bf[4];
            #pragma unroll
            for (int i = 0; i < 4; i++){
                int ra = wr*64 + i*16 + l15;
                af[i] = *(const short8*)&Al[cur][ra*BK + ((cc ^ (ra & 7)) * 8)];
                int rbb = wc*64 + i*16 + l15;
                bf[i] = *(const short8*)&Bl[cur][rbb*BK + ((cc ^ (rbb & 7)) * 8)];
            }
            #pragma unroll
            for (int i = 0; i < 4; i++){
                #pragma unroll
                for (int j = 0; j < 4; j++)
                    acc[i][j] = __builtin_amdgcn_mfma_f32_16x16x32_bf16(af[i], bf[j], acc[i][j], 0, 0, 0);
            }
        }
        __syncthreads();
    }

    // epilogue: C/D layout col=lane&15, row=(lane>>4)*4+q  [m89-verified]
    if (nsplit > 1){
        float* pp = part + (size_t)blockIdx.z * ((size_t)MDIM * NDIM);
        #pragma unroll
        for (int i = 0; i < 4; i++){
            #pragma unroll
            for (int j = 0; j < 4; j++){
                int col = n0 + wc*64 + j*16 + l15;
                #pragma unroll
                for (int q = 0; q < 4; q++){
                    int row = m0 + wr*64 + i*16 + (lane >> 4)*4 + q;
                    pp[(size_t)row * NDIM + col] = acc[i][j][q];
                }
            }
        }
    } else {
        #pragma unroll
        for (int i = 0; i < 4; i++){
            #pragma unroll
            for (int j = 0; j < 4; j++){
                int col = n0 + wc*64 + j*16 + l15;
                int d = col / AN, r = col - d*AN;
                #pragma unroll
                for (int q = 0; q < 4; q++){
                    int row = m0 + wr*64 + i*16 + (lane >> 4)*4 + q;
                    int b = row >> 10, pp2 = row & 1023;
                    out[((size_t)((b << 6) + d) * PN + pp2) * AN + r] = acc[i][j][q];
                }
            }
        }
    }
}

// ---------------- Kernel 5: split-K reduce + scatter to bdpr ----------------
__global__ __launch_bounds__(256) void k_reduce(const float* __restrict__ part,
                                                float* __restrict__ out, int nsplit)
{
    int t = blockIdx.x * 256 + threadIdx.x;        // per float4: MDIM*NDIM/4
    if (t >= MDIM * (NDIM/4)) return;
    int m = t / (NDIM/4);
    int n4 = (t - m * (NDIM/4)) * 4;
    f32x4 s = {};
    for (int z = 0; z < nsplit; z++){
        f32x4 v = *(const f32x4*)(part + (size_t)z * ((size_t)MDIM * NDIM) + (size_t)m * NDIM + n4);
        s += v;
    }
    int b = m >> 10, p = m & 1023;
    int d = n4 / AN, r = n4 - d*AN;    // r in {0,4,8}: never crosses d within 4
    *(f32x4*)(out + ((size_t)((b << 6) + d) * PN + p) * AN + r) = s;
}

extern "C" void kernel_launch(void* const* d_in, const int* in_sizes, int n_in,
                              void* d_out, int out_size, void* d_ws, size_t ws_size,
                              hipStream_t stream)
{
    const int*   nbr     = (const int*)  d_in[0];
    const float* vert    = (const float*)d_in[1];
    const float* fm      = (const float*)d_in[2];
    const float* W       = (const float*)d_in[3];
    const float* vs      = (const float*)d_in[4];
    const int*   idx_map = (const int*)  d_in[5];
    const int*   tiv     = (const int*)  d_in[6];
    const int*   tir     = (const int*)  d_in[7];
    float* out = (float*)d_out;

    char* ws = (char*)d_ws;
    float*          iw   = (float*)ws;                                  // 3,145,728 B
    unsigned short* Bm   = (unsigned short*)(ws + 3145728);             // 15,335,424 B
    unsigned short* Am   = (unsigned short*)(ws + 18481152);            // 81,788,928 B
    float*          part = (float*)(ws + 100270080);

    // split-K: valid values keep klen a multiple of BK=64 (KDIM = 156*64)
    long long avail = (long long)ws_size - 100270080LL;
    int maxs = (int)(avail / 12582912LL);
    int nsplit = (maxs >= 6) ? 6 : (maxs >= 4) ? 4 : (maxs >= 3) ? 3 : (maxs >= 2) ? 2 : 1;
    int klen = KDIM / nsplit;

    k_interw <<<(MDIM*AN)/256, 256, 0, stream>>>(nbr, vert, vs, iw);
    k_beff   <<<(C2N*AN*C1N*KN)/256, 256, 0, stream>>>(W, idx_map, tiv, tir, Bm);
    k_tr     <<<(BN*C1N*PN*3)/256, 256, 0, stream>>>(fm, Am);
    k_newfeat<<<MDIM/2, 256, 0, stream>>>(nbr, iw, Am);
    dim3 g(MDIM/128, NDIM/128, nsplit);
    k_gemm   <<<g, 256, 0, stream>>>(Am, Bm, part, out, klen, nsplit);
    if (nsplit > 1)
        k_reduce<<<(MDIM*(NDIM/4))/256, 256, 0, stream>>>(part, out, nsplit);
}